// Round 7
// baseline (56.978 us; speedup 1.0000x reference)
//
#include <hip/hip_runtime.h>
#include <hip/hip_bf16.h>
#include <math.h>

#define N 64
#define BATCH 2
#define PLANE (N * N)            // 4096
#define VOL (BATCH * N * N * N)  // 524288 elements per slot
#define BIGF 1e8f
#define LP 65                    // padded LDS stride
#define FBIG 3.4e38f
#define MASK1 0x17u              // labels {0,1,2,4}
#define MASK2 0x13u              // labels {0,1,4}

// ---------------------------------------------------------------------------
// Workspace (bytes):
//   [0, 8*VOL): ushort mids, 4 slots x VOL — slot m = tdm_m, slot 2+m = lz0_m
//              (exact: values <= 7938; 65535 = BIG sentinel)
//   at 8*VOL:             uint64 bits[2][BATCH*N*N]   (boundary y-bitmasks)
//   at 8*VOL + 131072:    float part[256][8]          (per-block partials)
//   at CTR_OFF:           int ctr[2]  (ctr[0]=grid barrier, ctr[1]=last-block)
// Phase-2 block m = bid>>7: m=0 -> tsd1 x bnd2 (h_outer); m=1 -> tsd2 x bnd1.
// ---------------------------------------------------------------------------

#define BITS_OFF ((size_t)8 * VOL)
#define PART_OFF (BITS_OFF + (size_t)2 * BATCH * N * N * 8)
#define CTR_OFF (PART_OFF + (size_t)256 * 8 * 4)

// Single persistent kernel: phase 1 = YZ passes for plane (m,b,x); device-wide
// barrier (256 blocks = 256 CUs, all co-resident; fence pattern validated by
// the r4/r5 last-block reduction); phase 2 = fused double X-envelope +
// hausdorff reduction for plane (m,b,y); last block writes d_out.
__global__ __launch_bounds__(512) void hausdorff_fused(
    const int* __restrict__ mmap, void* __restrict__ wsv,
    float* __restrict__ out) {
  __shared__ unsigned char colb[3][8][64];     // lz bits: plane, y-chunk, z
  __shared__ unsigned long long colm[3][64];   // column masks per plane, z
  __shared__ unsigned long long zmT[64];       // tdm zero-sites per z
  __shared__ unsigned long long zmL[64];       // levelzero zero-sites per z
  __shared__ float Bm1[N][LP];                 // phase1: Y/Z tiles; phase2: A1
  __shared__ float Bm2[N][LP];                 // phase1: Y/Z tiles; phase2: A2
  __shared__ float redS[8], redM[8], redB[8];
  __shared__ int lastFlag;

  const int bid = blockIdx.x;
  const int m = bid >> 7;
  const int plane = bid & 127;
  const int b = plane >> 6;
  const int t = threadIdx.x;
  const int z = t & 63, c = t >> 6;            // chunk c: y in [8c, 8c+8)
  const unsigned lmask = m ? MASK2 : MASK1;
  int* ctr = (int*)((char*)wsv + CTR_OFF);

  // ======================== PHASE 1: plane (m, b, x) ========================
  {
    const int x = plane & 63;
    const size_t bbase = (size_t)(b * N) * PLANE;

    // ---- load 3 planes' lz bits (x-1, x, x+1) ----
    #pragma unroll
    for (int p = 0; p < 3; ++p) {
      const int xp = x + p - 1;
      unsigned byte = 0;
      if (xp >= 0 && xp < N) {
        const size_t pb = bbase + (size_t)xp * PLANE;
        #pragma unroll
        for (int k = 0; k < 8; ++k) {
          const int y = 8 * c + k;
          byte |= ((lmask >> mmap[pb + y * N + z]) & 1u) << k;
        }
      }
      colb[p][c][z] = (unsigned char)byte;
    }
    __syncthreads();
    if (t < 192) {
      const int p = t >> 6, zz = t & 63;
      unsigned long long v = 0;
      #pragma unroll
      for (int cc = 0; cc < 8; ++cc)
        v |= (unsigned long long)colb[p][cc][zz] << (8 * cc);
      colm[p][zz] = v;
    }
    __syncthreads();
    // ---- derive zero-site masks + boundary bits (one thread per z) ----
    if (t < 64) {
      const unsigned long long cx = colm[1][t];
      unsigned long long nb = colm[0][t] | colm[2][t] | (cx << 1) | (cx >> 1);
      if (t > 0) nb |= colm[1][t - 1];
      if (t < 63) nb |= colm[1][t + 1];
      zmT[t] = ~cx;        // tdm EDT zero-set: lz==0
      zmL[t] = cx | nb;    // levelzero EDT zero-set: lz | dilation
      unsigned long long* bits = (unsigned long long*)((char*)wsv + BITS_OFF) +
                                 (size_t)m * (BATCH * N * N);
      bits[(size_t)(b * N + x) * N + t] = nb & ~cx;  // boundary: b==1
    }
    __syncthreads();

    // ---- exact Y-scan via clz/ffs on 64-bit column masks (+z^2 folded) ----
    {
      const unsigned long long M0 = zmT[z];
      const unsigned long long M1 = zmL[z];
      const float zs = (float)(z * z);
      #pragma unroll
      for (int k = 0; k < 8; ++k) {
        const int y = 8 * c + k;
        {
          const unsigned long long lo = M0 << (63 - y);
          const int dl = __clzll((long long)lo);
          const int f = __ffsll((long long)(M0 >> y));
          const int d = min(dl, f ? (f - 1) : 99);
          Bm1[y][z] = (d > 63) ? BIGF : (float)(d * d) + zs;
        }
        {
          const unsigned long long lo = M1 << (63 - y);
          const int dl = __clzll((long long)lo);
          const int f = __ffsll((long long)(M1 >> y));
          const int d = min(dl, f ? (f - 1) : 99);
          Bm2[y][z] = (d > 63) ? BIGF : (float)(d * d) + zs;
        }
      }
    }
    __syncthreads();

    // ---- two Z-envelopes: out = zz^2 + min_j (Bm[j] - 2 j zz) ----
    const int y = t & 63, w = t >> 6;
    float a1[8], a2[8], zq[8];
    #pragma unroll
    for (int q = 0; q < 8; ++q) {
      a1[q] = FBIG; a2[q] = FBIG; zq[q] = (float)(w + 8 * q);
    }
    float m2j = 0.f;
    #pragma unroll 2
    for (int j = 0; j < N; ++j) {
      const float f1 = Bm1[y][j];
      const float f2 = Bm2[y][j];
      #pragma unroll
      for (int q = 0; q < 8; ++q) {
        a1[q] = fminf(a1[q], fmaf(m2j, zq[q], f1));
        a2[q] = fminf(a2[q], fmaf(m2j, zq[q], f2));
      }
      m2j -= 2.f;
    }
    __syncthreads();  // all reads of Bm done before overwrite
    #pragma unroll
    for (int q = 0; q < 8; ++q) {
      Bm1[y][w + 8 * q] = fmaf(zq[q], zq[q], a1[q]);
      Bm2[y][w + 8 * q] = fmaf(zq[q], zq[q], a2[q]);
    }
    __syncthreads();
    unsigned short* mid1 = (unsigned short*)wsv + (size_t)m * VOL;
    unsigned short* mid2 = (unsigned short*)wsv + (size_t)(2 + m) * VOL;
    const size_t pbase = (size_t)(b * N + x) * PLANE;
    #pragma unroll
    for (int k = 0; k < 8; ++k) {
      const int e = t + 512 * k;
      mid1[pbase + e] = (unsigned short)fminf(Bm1[e >> 6][e & 63], 65535.f);
      mid2[pbase + e] = (unsigned short)fminf(Bm2[e >> 6][e & 63], 65535.f);
    }
  }

  // ===================== GRID BARRIER (256 blocks) ==========================
  __syncthreads();
  if (t == 0) {
    __threadfence();               // release: mids + bits visible device-scope
    atomicAdd(&ctr[0], 1);
    while (__hip_atomic_load(&ctr[0], __ATOMIC_ACQUIRE,
                             __HIP_MEMORY_SCOPE_AGENT) < 256) {
      __builtin_amdgcn_s_sleep(2);
    }
    __threadfence();               // acquire
  }
  __syncthreads();

  // ======================== PHASE 2: plane (m, b, y) ========================
  {
    const int y = plane & 63;
    const int w = t >> 6;  // w in [0,8)

    const unsigned short* mid1 = (const unsigned short*)wsv + (size_t)m * VOL;
    const unsigned short* mid2 =
        (const unsigned short*)wsv + (size_t)(2 + m) * VOL;
    #pragma unroll
    for (int k = 0; k < 8; ++k) {
      const int e = t + 512 * k;
      const int xx = e >> 6, zz = e & 63;
      const float xs = (float)(xx * xx);
      const size_t idx = (size_t)(b * N + xx) * PLANE + y * N + zz;
      const unsigned v1 = mid1[idx];
      const unsigned v2 = mid2[idx];
      Bm1[xx][zz] = ((v1 == 65535u) ? BIGF : (float)v1) + xs;  // + j^2 folded
      Bm2[xx][zz] = ((v2 == 65535u) ? BIGF : (float)v2) + xs;
    }
    __syncthreads();

    float a1[8], a2[8], xq[8];
    #pragma unroll
    for (int q = 0; q < 8; ++q) {
      a1[q] = FBIG; a2[q] = FBIG; xq[q] = (float)(w + 8 * q);
    }
    float m2j = 0.f;
    #pragma unroll 2
    for (int j = 0; j < N; ++j) {
      const float f1 = Bm1[j][z];
      const float f2 = Bm2[j][z];
      #pragma unroll
      for (int q = 0; q < 8; ++q) {
        a1[q] = fminf(a1[q], fmaf(m2j, xq[q], f1));
        a2[q] = fminf(a2[q], fmaf(m2j, xq[q], f2));
      }
      m2j -= 2.f;
    }

    // epilogue: tsd = sqrt(e_tdm) - sqrt(e_lz0); h = bnd_partner * |tsd|
    const unsigned long long* bits =
        (const unsigned long long*)((char*)wsv + BITS_OFF) +
        (size_t)(m == 0 ? 1 : 0) * (BATCH * N * N);
    float hsum = 0.f, hmax = 0.f, bsum = 0.f;
    #pragma unroll
    for (int q = 0; q < 8; ++q) {
      const float e1 = fmaf(xq[q], xq[q], a1[q]);
      const float e2 = fmaf(xq[q], xq[q], a2[q]);
      const float tsd = sqrtf(e1) - sqrtf(e2);
      const int xx = w + 8 * q;
      const unsigned long long bv = bits[(size_t)(b * N + xx) * N + z];
      const float bnd = (float)((bv >> y) & 1ull);
      const float h = bnd * fabsf(tsd);
      hsum += h; bsum += bnd; hmax = fmaxf(hmax, h);
    }
    #pragma unroll
    for (int o = 32; o > 0; o >>= 1) {
      hsum += __shfl_down(hsum, o);
      bsum += __shfl_down(bsum, o);
      hmax = fmaxf(hmax, __shfl_down(hmax, o));
    }
    if (z == 0) { redS[w] = hsum; redB[w] = bsum; redM[w] = hmax; }
    __syncthreads();

    float* part = (float*)((char*)wsv + PART_OFF);
    if (t == 0) {
      float s = 0.f, bs = 0.f, mx = 0.f;
      #pragma unroll
      for (int i = 0; i < 8; ++i) {
        s += redS[i]; bs += redB[i]; mx = fmaxf(mx, redM[i]);
      }
      float* p = part + (size_t)bid * 8;
      p[0] = s; p[1] = bs; p[2] = mx;
      __threadfence();
      const int old = atomicAdd(&ctr[1], 1);
      lastFlag = (old == 255) ? 1 : 0;
    }
    __syncthreads();
    if (lastFlag) {
      __threadfence();  // acquire: other blocks' part[] stores
      float s = 0.f, bs = 0.f, mx = 0.f;
      if (t < 256) {
        const float* p = part + (size_t)t * 8;
        s = p[0]; bs = p[1]; mx = p[2];
      }
      #pragma unroll
      for (int o = 32; o > 0; o >>= 1) {
        s += __shfl_down(s, o);
        bs += __shfl_down(bs, o);
        mx = fmaxf(mx, __shfl_down(mx, o));
      }
      __syncthreads();  // red arrays reuse
      if ((t & 63) == 0 && t < 256) {
        redS[t >> 6] = s; redB[t >> 6] = bs; redM[t >> 6] = mx;
      }
      __syncthreads();
      if (t == 0) {
        // partial idx p<128 -> m=0 (h_outer, bnd2) -> waves 0,1
        const float s_ho = redS[0] + redS[1], b2 = redB[0] + redB[1];
        const float mho = fmaxf(redM[0], redM[1]);
        const float s_hi = redS[2] + redS[3], b1 = redB[2] + redB[3];
        const float mhi = fmaxf(redM[2], redM[3]);
        const float him = s_hi / b1;
        const float hom = s_ho / b2;
        out[0] = him;
        out[1] = mhi;
        out[2] = hom;
        out[3] = mho;
        out[4] = (him - 2.f) * (him - 2.f) + (hom - 2.f) * (hom - 2.f);
      }
    }
  }
}

extern "C" void kernel_launch(void* const* d_in, const int* in_sizes, int n_in,
                              void* d_out, int out_size, void* d_ws,
                              size_t ws_size, hipStream_t stream) {
  (void)in_sizes; (void)n_in; (void)out_size; (void)ws_size;
  const int* mmap = (const int*)d_in[0];
  float* out = (float*)d_out;

  // zero the two counters (graph-capture-safe async memset, 8 bytes)
  hipMemsetAsync((char*)d_ws + CTR_OFF, 0, 8, stream);
  hausdorff_fused<<<2 * BATCH * N, 512, 0, stream>>>(mmap, d_ws, out);
}

// Round 8
// 37.324 us; speedup vs baseline: 1.5266x; 1.5266x over previous
//
#include <hip/hip_runtime.h>
#include <math.h>

#define N 64
#define PLANE 4096
#define FBIG 3.4e38f
#define MASK1 0x17u              // labels {0,1,2,4} (pair 1)
#define MASK2 0x13u              // labels {0,1,4}   (pair 2)
typedef unsigned long long ull;

// ---------------------------------------------------------------------------
// Workspace (bytes):
//   [0, 131072): ull cx[m][b][x][z] — y-column occupancy bitmasks (4 x 32 KB)
//   PART_OFF: float part[256][8] — per-stage2-block partials
//   CTR_OFF:  int ctr — stage2 completion counter (memset to 0 each call)
// Stage-2 block bid = (m*2+b)*64 + y0. m=0: tsd1 x bnd2 (h_outer); m=1: tsd2 x bnd1.
// ---------------------------------------------------------------------------
#define PART_OFF ((size_t)131072)
#define CTR_OFF (PART_OFF + (size_t)256 * 8 * 4)

// Stage 1: binarize mmap -> y-column bitmasks for both label masks.
__global__ __launch_bounds__(512) void build_bits(const int* __restrict__ mmap,
                                                  void* __restrict__ wsv) {
  __shared__ unsigned char colb[2][8][64];
  const int bid = blockIdx.x;       // b*64 + x
  const int b = bid >> 6, x = bid & 63;
  const int t = threadIdx.x;
  const int z = t & 63, c = t >> 6;
  const size_t pb = (size_t)(b * N + x) * PLANE;
  unsigned b1 = 0, b2 = 0;
  #pragma unroll
  for (int k = 0; k < 8; ++k) {
    const int v = mmap[pb + (8 * c + k) * N + z];
    b1 |= ((MASK1 >> v) & 1u) << k;
    b2 |= ((MASK2 >> v) & 1u) << k;
  }
  colb[0][c][z] = (unsigned char)b1;
  colb[1][c][z] = (unsigned char)b2;
  __syncthreads();
  if (t < 128) {
    const int mm = t >> 6, zz = t & 63;
    ull v = 0;
    #pragma unroll
    for (int cc = 0; cc < 8; ++cc)
      v |= (ull)colb[mm][cc][zz] << (8 * cc);
    ((ull*)wsv)[((size_t)(mm * 2 + b) * 64 + x) * 64 + zz] = v;
  }
}

// Stage 2: one block per (m, b, y0). Everything in LDS from bit-volumes.
__global__ __launch_bounds__(512) void edt_all(void* __restrict__ wsv,
                                               float* __restrict__ out) {
  __shared__ unsigned int g1p[64][65];   // packed u16: lo=T, hi=L; z'^2 folded
  __shared__ float g2T[64][65];          // Z-env out + x^2 folded
  __shared__ float g2L[64][65];
  __shared__ unsigned char bndB[4096];   // partner boundary bit at y0 per (x,z)
  __shared__ float redS[8], redB[8], redM[8];
  __shared__ int lastFlag;
  const int bid = blockIdx.x;            // (m*2+b)*64 + y0
  const int m = bid >> 7;
  const int y0 = bid & 63;
  const int t = threadIdx.x;

  const ull* cxO = (const ull*)wsv + ((size_t)(bid >> 6) & 3) * 4096;
  const ull* cxP = (const ull*)wsv + (size_t)(((1 - m) * 2) + ((bid >> 6) & 1)) * 4096;

  // ---- phase A: Y-eval at y0 (own tdm + levelzero) + partner bnd bit ----
  #pragma unroll
  for (int k = 0; k < 8; ++k) {
    const int ci = t + 512 * k;
    const int x = ci >> 6, z = ci & 63;
    const ull c0 = cxO[ci];
    const ull xm = (x > 0) ? cxO[ci - 64] : 0ull;
    const ull xp = (x < 63) ? cxO[ci + 64] : 0ull;
    const ull zm = (z > 0) ? cxO[ci - 1] : 0ull;
    const ull zp = (z < 63) ? cxO[ci + 1] : 0ull;
    const ull mT = ~c0;                                    // tdm zero-set
    const ull nb = xm | xp | zm | zp | (c0 << 1) | (c0 >> 1);
    const ull mL = c0 | nb;                                // levelzero zero-set
    const int zs = z * z;
    unsigned vT, vL;
    {
      const ull hi = mT >> y0;
      const int du = hi ? (__ffsll((long long)hi) - 1) : 99;
      const int dd = (int)__clzll((long long)(mT << (63 - y0)));  // 64 if none
      const int d = min(du, dd);
      vT = (d > 63) ? 65535u : (unsigned)(d * d + zs);
    }
    {
      const ull hi = mL >> y0;
      const int du = hi ? (__ffsll((long long)hi) - 1) : 99;
      const int dd = (int)__clzll((long long)(mL << (63 - y0)));
      const int d = min(du, dd);
      vL = (d > 63) ? 65535u : (unsigned)(d * d + zs);
    }
    g1p[x][z] = vT | (vL << 16);
    // partner boundary: bnd = dilate(cx') & ~cx', bit y0
    const ull p0 = cxP[ci];
    const ull pxm = (x > 0) ? cxP[ci - 64] : 0ull;
    const ull pxp = (x < 63) ? cxP[ci + 64] : 0ull;
    const ull pzm = (z > 0) ? cxP[ci - 1] : 0ull;
    const ull pzp = (z < 63) ? cxP[ci + 1] : 0ull;
    const ull pnb = pxm | pxp | pzm | pzp | (p0 << 1) | (p0 >> 1);
    bndB[ci] = (unsigned char)(((pnb & ~p0) >> y0) & 1ull);
  }
  __syncthreads();

  // ---- phase B: Z-envelope. Thread owns x = t>>3, outputs z = g+8q. ----
  {
    const int x = t >> 3, g = t & 7;
    float aT[8], aL[8], zq[8];
    #pragma unroll
    for (int q = 0; q < 8; ++q) {
      aT[q] = FBIG; aL[q] = FBIG; zq[q] = (float)(g + 8 * q);
    }
    const unsigned* row = &g1p[x][0];
    float m2j = 0.f;
    #pragma unroll 4
    for (int j = 0; j < 64; ++j) {
      const unsigned v = row[j];
      const float fT = (float)(v & 0xffffu);
      const float fL = (float)(v >> 16);
      #pragma unroll
      for (int q = 0; q < 8; ++q) {
        aT[q] = fminf(aT[q], fmaf(m2j, zq[q], fT));
        aL[q] = fminf(aL[q], fmaf(m2j, zq[q], fL));
      }
      m2j -= 2.f;
    }
    const float xs = (float)(x * x);
    #pragma unroll
    for (int q = 0; q < 8; ++q) {
      const int zi = g + 8 * q;
      const float z2 = zq[q] * zq[q];
      g2T[x][zi] = aT[q] + z2 + xs;  // g2true + x^2 folded for X-env
      g2L[x][zi] = aL[q] + z2 + xs;
    }
  }
  __syncthreads();

  // ---- phase C: X-envelope + epilogue. Thread owns z = t>>3, x = g+8q. ----
  {
    const int z = t >> 3, g = t & 7;
    float aT[8], aL[8], xq[8];
    #pragma unroll
    for (int q = 0; q < 8; ++q) {
      aT[q] = FBIG; aL[q] = FBIG; xq[q] = (float)(g + 8 * q);
    }
    float m2j = 0.f;
    #pragma unroll 4
    for (int j = 0; j < 64; ++j) {
      const float f1 = g2T[j][z];
      const float f2 = g2L[j][z];
      #pragma unroll
      for (int q = 0; q < 8; ++q) {
        aT[q] = fminf(aT[q], fmaf(m2j, xq[q], f1));
        aL[q] = fminf(aL[q], fmaf(m2j, xq[q], f2));
      }
      m2j -= 2.f;
    }
    float hsum = 0.f, bsum = 0.f, hmax = 0.f;
    #pragma unroll
    for (int q = 0; q < 8; ++q) {
      const int x = g + 8 * q;
      const float eT = fmaf(xq[q], xq[q], aT[q]);
      const float eL = fmaf(xq[q], xq[q], aL[q]);
      const float tsd = sqrtf(eT) - sqrtf(eL);
      const float bnd = (float)bndB[x * 64 + z];
      const float h = bnd * fabsf(tsd);
      hsum += h; bsum += bnd; hmax = fmaxf(hmax, h);
    }
    #pragma unroll
    for (int o = 32; o > 0; o >>= 1) {
      hsum += __shfl_down(hsum, o);
      bsum += __shfl_down(bsum, o);
      hmax = fmaxf(hmax, __shfl_down(hmax, o));
    }
    const int w = t >> 6;
    if ((t & 63) == 0) { redS[w] = hsum; redB[w] = bsum; redM[w] = hmax; }
  }
  __syncthreads();

  float* part = (float*)((char*)wsv + PART_OFF);
  int* ctr = (int*)((char*)wsv + CTR_OFF);
  if (t == 0) {
    float s = 0.f, bs = 0.f, mx = 0.f;
    #pragma unroll
    for (int i = 0; i < 8; ++i) {
      s += redS[i]; bs += redB[i]; mx = fmaxf(mx, redM[i]);
    }
    float* p = part + (size_t)bid * 8;
    p[0] = s; p[1] = bs; p[2] = mx;
    __threadfence();
    const int old = atomicAdd(ctr, 1);
    lastFlag = (old == 255) ? 1 : 0;
  }
  __syncthreads();
  if (lastFlag) {
    __threadfence();  // acquire other blocks' partials
    float s = 0.f, bs = 0.f, mx = 0.f;
    if (t < 256) {
      const float* p = part + (size_t)t * 8;
      s = p[0]; bs = p[1]; mx = p[2];
    }
    #pragma unroll
    for (int o = 32; o > 0; o >>= 1) {
      s += __shfl_down(s, o);
      bs += __shfl_down(bs, o);
      mx = fmaxf(mx, __shfl_down(mx, o));
    }
    __syncthreads();
    if ((t & 63) == 0 && t < 256) {
      redS[t >> 6] = s; redB[t >> 6] = bs; redM[t >> 6] = mx;
    }
    __syncthreads();
    if (t == 0) {
      // partials p<128 are m=0: h_outer sums + bnd2; p>=128: h_inner + bnd1
      const float s_ho = redS[0] + redS[1], b2 = redB[0] + redB[1];
      const float mho = fmaxf(redM[0], redM[1]);
      const float s_hi = redS[2] + redS[3], b1 = redB[2] + redB[3];
      const float mhi = fmaxf(redM[2], redM[3]);
      const float him = s_hi / b1;
      const float hom = s_ho / b2;
      out[0] = him;
      out[1] = mhi;
      out[2] = hom;
      out[3] = mho;
      out[4] = (him - 2.f) * (him - 2.f) + (hom - 2.f) * (hom - 2.f);
    }
  }
}

extern "C" void kernel_launch(void* const* d_in, const int* in_sizes, int n_in,
                              void* d_out, int out_size, void* d_ws,
                              size_t ws_size, hipStream_t stream) {
  (void)in_sizes; (void)n_in; (void)out_size; (void)ws_size;
  const int* mmap = (const int*)d_in[0];
  float* out = (float*)d_out;

  hipMemsetAsync((char*)d_ws + CTR_OFF, 0, 8, stream);
  build_bits<<<128, 512, 0, stream>>>(mmap, d_ws);
  edt_all<<<256, 512, 0, stream>>>(d_ws, out);
}